// Round 1
// baseline (633.610 us; speedup 1.0000x reference)
//
#include <hip/hip_runtime.h>

// VQ-VAE fused forward on gfx950.
// Pipeline per 64-row block: x --[G1 K=512]--> h1(64) --[G2]--> h2(256)
//   --[G3]--> lat(256) --[G4 vs 1024 protos]--> argmin --> gather q, loss.
// All GEMMs: mfma_f32_16x16x32_bf16, f32 accum. Weights pre-cast to bf16 in ws.
// out[0..N*256) = q rows (exact f32 gather); out[N*256] = vq_loss; out[+1] = 0.

typedef unsigned short u16;
typedef float f32x4 __attribute__((ext_vector_type(4)));
typedef __bf16 bf16x8 __attribute__((ext_vector_type(8)));
typedef unsigned short u16x8 __attribute__((ext_vector_type(8)));
typedef unsigned short u16x4 __attribute__((ext_vector_type(4)));

#define N_ROWS 131072
#define IN_D 512
#define HID_D 64
#define OUT_D 256
#define K_P 1024

__device__ __forceinline__ u16 f2bf(float f) {
  unsigned u = __builtin_bit_cast(unsigned, f);
  u += 0x7FFFu + ((u >> 16) & 1u);   // RTNE
  return (u16)(u >> 16);
}
__device__ __forceinline__ float bf2f(u16 h) {
  unsigned u = ((unsigned)h) << 16;
  return __builtin_bit_cast(float, u);
}
__device__ __forceinline__ f32x4 mfma16(u16x8 a, u16x8 b, f32x4 c) {
  return __builtin_amdgcn_mfma_f32_16x16x32_bf16(
      __builtin_bit_cast(bf16x8, a), __builtin_bit_cast(bf16x8, b), c, 0, 0, 0);
}
// XOR-swizzled LDS addressing (u16 units), 16B chunks; avoids padding so the
// two 32KB regions total exactly 64KB. Residual 2-way bank aliasing is free.
__device__ __forceinline__ int sw128(int row, int col) {  // [64][128]
  return row * 128 + ((((col >> 3) ^ (row & 15)) & 15) << 3) + (col & 7);
}
__device__ __forceinline__ int sw64(int row, int col) {   // [64][64]
  return row * 64 + ((((col >> 3) ^ (row & 7)) & 7) << 3) + (col & 7);
}
__device__ __forceinline__ int sw256(int row, int col) {  // [64][256]
  return row * 256 + ((((col >> 3) ^ (row & 15)) & 31) << 3) + (col & 7);
}

// ---------------- prep kernels ----------------
__global__ void prep_w(const float* __restrict__ W1, const float* __restrict__ W2,
                       const float* __restrict__ Wmu, u16* __restrict__ w1b,
                       u16* __restrict__ w2b, u16* __restrict__ wmub,
                       float* __restrict__ loss_accum) {
  int i = blockIdx.x * 256 + threadIdx.x;   // grid 448*256 = 114688 exactly
  if (i == 0) *loss_accum = 0.f;
  if (i < 32768) {
    w1b[i] = f2bf(W1[i]);
  } else if (i < 49152) {
    w2b[i - 32768] = f2bf(W2[i - 32768]);
  } else {
    wmub[i - 49152] = f2bf(Wmu[i - 49152]);
  }
}

__global__ void prep_p(const float* __restrict__ protos, u16* __restrict__ protosb,
                       float* __restrict__ pnorm) {
  int b = blockIdx.x, t = threadIdx.x;      // 1024 blocks x 256 threads
  float v = protos[b * 256 + t];
  protosb[b * 256 + t] = f2bf(v);
  float s = v * v;
  for (int off = 32; off; off >>= 1) s += __shfl_xor(s, off, 64);
  __shared__ float red[4];
  if ((t & 63) == 0) red[t >> 6] = s;
  __syncthreads();
  if (t == 0) pnorm[b] = red[0] + red[1] + red[2] + red[3];
}

__global__ void fin(const float* __restrict__ loss_accum, float* __restrict__ out) {
  out[(size_t)N_ROWS * OUT_D] = loss_accum[0] * (1.25f / ((float)N_ROWS * (float)OUT_D));
  out[(size_t)N_ROWS * OUT_D + 1] = 0.f;  // capacity (int32 0 == f32 0 bits)
}

// ---------------- fused main kernel ----------------
__global__ __launch_bounds__(256, 2) void vq_fused(
    const float* __restrict__ x, const float* __restrict__ b1,
    const float* __restrict__ b2, const float* __restrict__ bmu,
    const float* __restrict__ protos, const u16* __restrict__ w1b,
    const u16* __restrict__ w2b, const u16* __restrict__ wmub,
    const u16* __restrict__ protosb, const float* __restrict__ pnorm,
    float* __restrict__ out, float* __restrict__ loss_accum) {
  __shared__ uint4 smem4[4096];                  // 64 KB exactly
  u16* sm = (u16*)smem4;
  u16* regA = sm;                                // xs -> h1s -> latb (sequential, barriered)
  u16* regB = sm + 16384;                        // h2s -> argmin scratch

  const int tid = threadIdx.x;
  const int wave = tid >> 6;
  const int lane = tid & 63;
  const int quad = lane >> 4;
  const int l15 = lane & 15;
  const long rowbase = (long)blockIdx.x * 64;

  // ===== GEMM1: h1 = relu(x @ W1^T + b1), K=512 in 4 chunks of 128 =====
  f32x4 acc1[4];
  for (int mt = 0; mt < 4; mt++) acc1[mt] = (f32x4){0.f, 0.f, 0.f, 0.f};
  for (int kc = 0; kc < 4; kc++) {
    __syncthreads();                             // prev chunk reads done
    {                                            // stage x[64][128] -> bf16 LDS
      int r = tid >> 2, seg = tid & 3;
      const float* xp = x + (rowbase + r) * IN_D + kc * 128 + seg * 32;
      for (int j = 0; j < 4; j++) {
        f32x4 v0 = ((const f32x4*)xp)[2 * j];
        f32x4 v1 = ((const f32x4*)xp)[2 * j + 1];
        u16x8 h;
        h[0] = f2bf(v0[0]); h[1] = f2bf(v0[1]); h[2] = f2bf(v0[2]); h[3] = f2bf(v0[3]);
        h[4] = f2bf(v1[0]); h[5] = f2bf(v1[1]); h[6] = f2bf(v1[2]); h[7] = f2bf(v1[3]);
        *((u16x8*)(regA + sw128(r, seg * 32 + j * 8))) = h;
      }
    }
    __syncthreads();
    for (int s = 0; s < 4; s++) {
      int kg = kc * 128 + s * 32;
      u16x8 bf = *((const u16x8*)(w1b + (wave * 16 + l15) * IN_D + kg + quad * 8));
      for (int mt = 0; mt < 4; mt++) {
        u16x8 af = *((const u16x8*)(regA + sw128(mt * 16 + l15, s * 32 + quad * 8)));
        acc1[mt] = mfma16(af, bf, acc1[mt]);
      }
    }
  }
  __syncthreads();                               // xs dead; regA becomes h1s
  {
    float bias = b1[wave * 16 + l15];            // wave owns hid cols w*16..+15
    for (int mt = 0; mt < 4; mt++)
      for (int r = 0; r < 4; r++) {
        float v = acc1[mt][r] + bias;
        v = v > 0.f ? v : 0.f;
        regA[sw64(mt * 16 + quad * 4 + r, wave * 16 + l15)] = f2bf(v);
      }
  }
  __syncthreads();                               // h1s complete (all waves)

  // ===== GEMM2: h2 = relu(h1 @ W2^T + b2), K=64; wave owns cols w*64..+63 =====
  {
    u16x8 b2f[4][2];
    float bias2[4];
    for (int nt = 0; nt < 4; nt++) {
      int col = wave * 64 + nt * 16 + l15;
      bias2[nt] = b2[col];
      for (int s = 0; s < 2; s++)
        b2f[nt][s] = *((const u16x8*)(w2b + col * HID_D + s * 32 + quad * 8));
    }
    for (int mt = 0; mt < 4; mt++) {
      u16x8 a0 = *((const u16x8*)(regA + sw64(mt * 16 + l15, 0 + quad * 8)));
      u16x8 a1 = *((const u16x8*)(regA + sw64(mt * 16 + l15, 32 + quad * 8)));
      for (int nt = 0; nt < 4; nt++) {
        f32x4 acc = (f32x4){0.f, 0.f, 0.f, 0.f};
        acc = mfma16(a0, b2f[nt][0], acc);
        acc = mfma16(a1, b2f[nt][1], acc);
        for (int r = 0; r < 4; r++) {
          float v = acc[r] + bias2[nt];
          v = v > 0.f ? v : 0.f;
          regB[sw256(mt * 16 + quad * 4 + r, wave * 64 + nt * 16 + l15)] = f2bf(v);
        }
      }
    }
  }
  __syncthreads();                               // h2s complete; regA free for latb

  // ===== GEMM3: lat = h2 @ Wmu^T + bmu, K=256; wave owns cols w*64..+63 =====
  for (int np = 0; np < 2; np++) {
    u16x8 b3f[2][8];
    float bias3[2];
    for (int tt = 0; tt < 2; tt++) {
      int col = wave * 64 + (np * 2 + tt) * 16 + l15;
      bias3[tt] = bmu[col];
      for (int s = 0; s < 8; s++)
        b3f[tt][s] = *((const u16x8*)(wmub + col * OUT_D + s * 32 + quad * 8));
    }
    for (int mt = 0; mt < 4; mt++) {
      f32x4 accs[2] = {(f32x4){0.f, 0.f, 0.f, 0.f}, (f32x4){0.f, 0.f, 0.f, 0.f}};
      for (int s = 0; s < 8; s++) {
        u16x8 af = *((const u16x8*)(regB + sw256(mt * 16 + l15, s * 32 + quad * 8)));
        accs[0] = mfma16(af, b3f[0][s], accs[0]);
        accs[1] = mfma16(af, b3f[1][s], accs[1]);
      }
      for (int tt = 0; tt < 2; tt++)
        for (int r = 0; r < 4; r++) {
          float v = accs[tt][r] + bias3[tt];     // NO relu on lat
          regA[sw256(mt * 16 + quad * 4 + r, wave * 64 + (np * 2 + tt) * 16 + l15)] = f2bf(v);
        }
    }
  }
  __syncthreads();                               // latb complete; h2s dead

  // ===== GEMM4: scores vs protos, argmin; wave owns protos w*256..+255 =====
  float minv[16];
  int mini[16];
  for (int i = 0; i < 16; i++) { minv[i] = 3.4e38f; mini[i] = 0; }
  for (int g = 0; g < 8; g++) {
    int p0 = wave * 256 + g * 32;
    u16x8 bpf[2][8];
    for (int tt = 0; tt < 2; tt++)
      for (int s = 0; s < 8; s++)
        bpf[tt][s] = *((const u16x8*)(protosb + (p0 + tt * 16 + l15) * OUT_D + s * 32 + quad * 8));
    float pn0 = pnorm[p0 + l15];
    float pn1 = pnorm[p0 + 16 + l15];
    for (int mt = 0; mt < 4; mt++) {
      f32x4 acca = (f32x4){0.f, 0.f, 0.f, 0.f}, accb = (f32x4){0.f, 0.f, 0.f, 0.f};
      for (int s = 0; s < 8; s++) {
        u16x8 af = *((const u16x8*)(regA + sw256(mt * 16 + l15, s * 32 + quad * 8)));
        acca = mfma16(af, bpf[0][s], acca);
        accb = mfma16(af, bpf[1][s], accb);
      }
      for (int r = 0; r < 4; r++) {
        float d0 = pn0 - 2.f * acca[r];          // ||lat||^2 constant per row: dropped
        float d1 = pn1 - 2.f * accb[r];
        int ii = mt * 4 + r;
        if (d0 < minv[ii]) { minv[ii] = d0; mini[ii] = p0 + l15; }
        if (d1 < minv[ii]) { minv[ii] = d1; mini[ii] = p0 + 16 + l15; }
      }
    }
  }
  // reduce argmin across the 16 cols (l15) within each quad
  for (int off = 1; off < 16; off <<= 1)
    for (int i = 0; i < 16; i++) {
      float ov = __shfl_xor(minv[i], off, 64);
      int oi = __shfl_xor(mini[i], off, 64);
      if (ov < minv[i] || (ov == minv[i] && oi < mini[i])) { minv[i] = ov; mini[i] = oi; }
    }
  float* wv = (float*)regB;                      // [4][64]
  int* wi = (int*)((char*)regB + 1024);          // [4][64]
  int* idxs = (int*)((char*)regB + 2048);        // [64]
  if (l15 == 0)
    for (int mt = 0; mt < 4; mt++)
      for (int r = 0; r < 4; r++) {
        int row = mt * 16 + quad * 4 + r;
        wv[wave * 64 + row] = minv[mt * 4 + r];
        wi[wave * 64 + row] = mini[mt * 4 + r];
      }
  __syncthreads();
  if (tid < 64) {                                // reduce across 4 waves per row
    float bv = wv[tid];
    int bi = wi[tid];
    for (int w = 1; w < 4; w++) {
      float v = wv[w * 64 + tid];
      int i2 = wi[w * 64 + tid];
      if (v < bv || (v == bv && i2 < bi)) { bv = v; bi = i2; }
    }
    idxs[tid] = bi;
  }
  __syncthreads();

  // ===== epilogue: out = protos[idx] (exact f32 gather), loss += (q-lat)^2 =====
  {
    int r = tid >> 2, seg = tid & 3;
    int idx = idxs[r];
    const f32x4* qp = (const f32x4*)(protos + (size_t)idx * OUT_D + seg * 64);
    f32x4* op = (f32x4*)(out + (rowbase + r) * OUT_D + seg * 64);
    float lsum = 0.f;
    for (int j = 0; j < 16; j++) {
      f32x4 q = qp[j];
      u16x4 lb = *((const u16x4*)(regA + sw256(r, seg * 64 + j * 4)));
      float d0 = q[0] - bf2f(lb[0]);
      float d1 = q[1] - bf2f(lb[1]);
      float d2 = q[2] - bf2f(lb[2]);
      float d3 = q[3] - bf2f(lb[3]);
      lsum += d0 * d0 + d1 * d1 + d2 * d2 + d3 * d3;
      op[j] = q;
    }
    for (int off = 32; off; off >>= 1) lsum += __shfl_xor(lsum, off, 64);
    if (lane == 0) atomicAdd(loss_accum, lsum);
  }
}

extern "C" void kernel_launch(void* const* d_in, const int* in_sizes, int n_in,
                              void* d_out, int out_size, void* d_ws, size_t ws_size,
                              hipStream_t stream) {
  const float* x = (const float*)d_in[0];
  const float* W1 = (const float*)d_in[1];
  const float* b1 = (const float*)d_in[2];
  const float* W2 = (const float*)d_in[3];
  const float* b2 = (const float*)d_in[4];
  const float* Wmu = (const float*)d_in[5];
  const float* bmu = (const float*)d_in[6];
  const float* protos = (const float*)d_in[7];
  char* ws = (char*)d_ws;
  u16* protosb = (u16*)ws;                       // 512 KB
  u16* w1b = (u16*)(ws + 524288);                // 64 KB
  u16* w2b = (u16*)(ws + 589824);                // 32 KB
  u16* wmub = (u16*)(ws + 622592);               // 128 KB
  float* pnorm = (float*)(ws + 753664);          // 4 KB
  float* loss = (float*)(ws + 757760);           // 4 B
  float* out = (float*)d_out;

  prep_w<<<dim3(448), dim3(256), 0, stream>>>(W1, W2, Wmu, w1b, w2b, wmub, loss);
  prep_p<<<dim3(1024), dim3(256), 0, stream>>>(protos, protosb, pnorm);
  vq_fused<<<dim3(2048), dim3(256), 0, stream>>>(x, b1, b2, bmu, protos, w1b, w2b,
                                                 wmub, protosb, pnorm, out, loss);
  fin<<<dim3(1), dim3(1), 0, stream>>>(loss, out);
}